// Round 14
// baseline (1039.991 us; speedup 1.0000x reference)
//
#include <hip/hip_runtime.h>
#include <math.h>

#define N0 120000
#define N1 60000
#define E0N 1500000
#define E1N 1000000
#define E2N 1000000
#define FIN 771
#define NG 64
#define KSTEPS_IN 25   // ceil(771/32)

#define GB0 ((N0 + 127) / 128)      // 938  (epi grid)
#define GB1 ((N1 + 127) / 128)      // 469
#define GB064 (N0 / 64)             // 1875 (inproj grid, N0 % 64 == 0)
#define GB164 ((N1 + 63) / 64)      // 938
#define AB0 ((N0 + 3) / 4)          // 30000
#define AB1 ((N1 + 3) / 4)          // 15000
#define SB0 ((N0 + 1023) / 1024)    // 118
#define SB1 ((N1 + 1023) / 1024)    // 59
#define PREPB 70                    // 16 fold + 50 win-pack + 4 wa-pack

// projAll BYTE offsets: all rows are 128 B.
#define Q0O   ((size_t)0)
#define KV00O ((size_t)N0 * 128)
#define KV02O ((size_t)N0 * 256)
#define Q1O   ((size_t)N0 * 384)
#define KV11O ((size_t)N0 * 384 + (size_t)N1 * 128)

#define SKV 256.0f            // fp8 pack scale for K and V
#define INV_SKV 0.00390625f

typedef __attribute__((ext_vector_type(8))) short short8;
typedef __attribute__((ext_vector_type(4))) float f32x4;
typedef __attribute__((ext_vector_type(2))) float f32x2;
typedef float f32x4u __attribute__((ext_vector_type(4), aligned(4)));
typedef __attribute__((ext_vector_type(4))) unsigned short ushort4v;
typedef unsigned short ushort;
typedef unsigned char uchar;

__device__ __forceinline__ float gelu_f(float v) {
    return 0.5f * v * (1.f + erff(v * 0.70710678118654752f));
}
__device__ __forceinline__ ushort f2b(float f) {
    union { float f; unsigned u; } v; v.f = f;
    unsigned u = v.u;
    return (ushort)((u + 0x7FFFu + ((u >> 16) & 1u)) >> 16);  // RNE
}
__device__ __forceinline__ float b2f(ushort h) {
    union { unsigned u; float f; } v; v.u = ((unsigned)h) << 16; return v.f;
}
__device__ __forceinline__ float lo16(unsigned u) {
    union { unsigned x; float f; } v; v.x = u << 16; return v.f;
}
__device__ __forceinline__ float hi16(unsigned u) {
    union { unsigned x; float f; } v; v.x = u & 0xFFFF0000u; return v.f;
}
__device__ __forceinline__ int asi(float f) { union { float f; int i; } v; v.f = f; return v.i; }
__device__ __forceinline__ float asf(int i) { union { int i; float f; } v; v.i = i; return v.f; }

// ---------------------------------------------------------------- proj phase (templated on rows)
// NRB = 16-row blocks per wave (1 => 64-row tile, 2 => 128-row tile).
// xls: [ROWS][72] bf16 xs rows. scratch: ROWS*128 B, XOR-swizzled.
template <int NRB>
__device__ __forceinline__ void proj_phase(
    const ushort* xls, char* scratch, int type, int l, int w, int lane, int tid,
    int r0b, int nrows,
    const ushort* __restrict__ Wpack, const float* __restrict__ bpack,
    uchar* __restrict__ projAll)
{
    const int ROWS = NRB * 64;
    short8 bfr[2][NRB];
    #pragma unroll
    for (int ksp = 0; ksp < 2; ++ksp)
        #pragma unroll
        for (int rb = 0; rb < NRB; ++rb)
            bfr[ksp][rb] = *(const short8*)&xls[(w * 16 * NRB + rb * 16 + (lane & 15)) * 72
                                                + ksp * 32 + (lane >> 4) * 8];
    const int sbase = l * 8 + (type ? 5 : 0);
    const int c0b = (lane >> 4) * 4;
    const int ngroups = type ? 2 : 3;

    for (int grp = 0; grp < ngroups; ++grp) {
        const int s0 = (grp == 0) ? 0 : (grp * 2 - 1);   // Q | (K1,V2) | (K3,V4)
        const int nsl = (grp == 0) ? 1 : 2;
        for (int si = 0; si < nsl; ++si) {
            const int slot = s0 + si;
            const ushort* Wp = Wpack + (size_t)(sbase + slot) * 4096;
            const float* bias = bpack + (size_t)(sbase + slot) * 64;
            f32x4 acc[NRB][4] = {};
            #pragma unroll
            for (int ksp = 0; ksp < 2; ++ksp) {
                const ushort* wb = Wp + ksp * 2048 + lane * 8;
                #pragma unroll
                for (int cg = 0; cg < 4; ++cg) {
                    short8 afr = *(const short8*)&wb[cg * 512];
                    #pragma unroll
                    for (int rb = 0; rb < NRB; ++rb)
                        acc[rb][cg] = __builtin_amdgcn_mfma_f32_16x16x32_bf16(afr, bfr[ksp][rb], acc[rb][cg], 0, 0, 0);
                }
            }
            #pragma unroll
            for (int rb = 0; rb < NRB; ++rb) {
                int lrow = w * 16 * NRB + rb * 16 + (lane & 15);
                const int sw = (lrow & 7) << 4;
                #pragma unroll
                for (int cg = 0; cg < 4; ++cg) {
                    int c = cg * 16 + c0b;
                    float v0 = acc[rb][cg][0] + bias[c + 0];
                    float v1 = acc[rb][cg][1] + bias[c + 1];
                    float v2 = acc[rb][cg][2] + bias[c + 2];
                    float v3 = acc[rb][cg][3] + bias[c + 3];
                    if (grp == 0) {
                        ushort4v o;
                        o[0] = f2b(v0); o[1] = f2b(v1); o[2] = f2b(v2); o[3] = f2b(v3);
                        *(ushort4v*)(scratch + lrow * 128 + ((c * 2) ^ sw)) = o;
                    } else {
                        int wrd = __builtin_amdgcn_cvt_pk_fp8_f32(v0 * SKV, v1 * SKV, 0, 0);
                        wrd = __builtin_amdgcn_cvt_pk_fp8_f32(v2 * SKV, v3 * SKV, wrd, 1);
                        *(int*)(scratch + lrow * 128 + ((((c >> 2) << 3) + (si << 2)) ^ sw)) = wrd;
                    }
                }
            }
        }
        __syncthreads();
        size_t ooff;
        if (grp == 0) ooff = type ? Q1O : Q0O;
        else if (grp == 1) ooff = type ? KV11O : KV00O;
        else ooff = KV02O;
        char* outg = (char*)projAll + ooff + (size_t)r0b * 128;
        #pragma unroll
        for (int q = 0; q < ROWS / 32; ++q) {
            int off = q * 4096 + tid * 16;
            int row = off >> 7;
            int inner = off & 127;
            if (r0b + row < nrows)
                *(uint4*)(outg + off) =
                    *(const uint4*)(scratch + row * 128 + (inner ^ ((row & 7) << 4)));
        }
        __syncthreads();
    }
}

// ---------------------------------------------------------------- in_proj + proj l=0
// 64-row slab per block: the tile's input is one CONTIGUOUS 197 KB region; 256 threads
// march it in strictly linear float4 order (memcpy pattern), converting to bf16 in LDS.
__global__ __launch_bounds__(256) void inproj_proj_kernel(
    const float* __restrict__ xa, const float* __restrict__ xe,
    const ushort* __restrict__ Wpin, const float* __restrict__ b_in,
    ushort* __restrict__ xs0, ushort* __restrict__ xs1,
    const ushort* __restrict__ Wpack, const float* __restrict__ bpack,
    uchar* __restrict__ projAll)
{
    __shared__ union {
        ushort xt[64 * 772];                                         // 98.8 KB
        struct { ushort xls[64 * 72]; char scratch[8192]; } pp;
    } sm;
    const int bx = blockIdx.x;
    const int type = (bx >= GB064) ? 1 : 0;
    const float* __restrict__ x = type ? xe : xa;
    const int nrows = type ? N1 : N0;
    const ushort* __restrict__ Wp = Wpin + (type ? (size_t)KSTEPS_IN * 2048 : 0);
    const float* __restrict__ bias = b_in + type * 64;
    ushort* __restrict__ out = type ? xs1 : xs0;

    const int tid = threadIdx.x, w = tid >> 6, lane = tid & 63;
    const int r0b = (type ? bx - GB064 : bx) * 64;

    // ---- linear slab staging: 64*771 = 49344 floats = 12336 float4s
    const float* __restrict__ src = x + (size_t)r0b * FIN;
    const int nelem = (min(r0b + 64, nrows) - r0b) * FIN;
    int e = tid * 4;
    int row = (e >= FIN) ? 1 : 0;
    int col = e - row * FIN;
    for (int b = 0; b < 6; ++b) {
        f32x4u v[8];
        #pragma unroll
        for (int i = 0; i < 8; ++i) {
            int ee = e + i * 1024;
            v[i] = (ee < nelem) ? *(const f32x4u*)(src + ee) : (f32x4u){};
        }
        #pragma unroll
        for (int i = 0; i < 8; ++i) {
            #pragma unroll
            for (int j = 0; j < 4; ++j) {
                int cc = col + j, rr = row;
                if (cc >= FIN) { cc -= FIN; ++rr; }
                sm.xt[rr * 772 + cc] = f2b(v[i][j]);
            }
            row += 1; col += 253;                 // advance by 1024 elements
            if (col >= FIN) { col -= FIN; row += 1; }
        }
        e += 8192;
    }
    if (tid < 48) {     // tail float4s 12288..12335, all in row 63
        int ee = 49152 + tid * 4;
        f32x4u v = (ee < nelem) ? *(const f32x4u*)(src + ee) : (f32x4u){};
        int cc = ee - 63 * FIN;                   // 579 + 4*tid <= 767
        #pragma unroll
        for (int j = 0; j < 4; ++j) sm.xt[63 * 772 + cc + j] = f2b(v[j]);
    }
    __syncthreads();

    // ---- MFMA from LDS: 16 rows per wave
    const int mrow = w * 16 + (lane & 15);
    f32x4 acc[4] = {};
    #pragma unroll
    for (int ks = 0; ks < 24; ++ks) {
        short8 bfr = *(const short8*)&sm.xt[mrow * 772 + ks * 32 + (lane >> 4) * 8];
        const ushort* wb = Wp + (size_t)ks * 2048 + lane * 8;
        #pragma unroll
        for (int cg = 0; cg < 4; ++cg) {
            short8 afr = *(const short8*)&wb[cg * 512];
            acc[cg] = __builtin_amdgcn_mfma_f32_16x16x32_bf16(afr, bfr, acc[cg], 0, 0, 0);
        }
    }
    {   // k-tail 768..770 (lane group 0, j<3 only; W zero-padded beyond)
        short8 bfr = {};
        if ((lane >> 4) == 0) {
            bfr[0] = (short)sm.xt[mrow * 772 + 768];
            bfr[1] = (short)sm.xt[mrow * 772 + 769];
            bfr[2] = (short)sm.xt[mrow * 772 + 770];
        }
        const ushort* wb = Wp + (size_t)24 * 2048 + lane * 8;
        #pragma unroll
        for (int cg = 0; cg < 4; ++cg) {
            short8 afr = *(const short8*)&wb[cg * 512];
            acc[cg] = __builtin_amdgcn_mfma_f32_16x16x32_bf16(afr, bfr, acc[cg], 0, 0, 0);
        }
    }
    __syncthreads();   // xt reads done; sm reused as xls/scratch

    const int c0b = (lane >> 4) * 4;
    const int r = r0b + mrow;
    #pragma unroll
    for (int cg = 0; cg < 4; ++cg) {
        int c = cg * 16 + c0b;
        ushort4v h;
        h[0] = f2b(fmaxf(acc[cg][0] + bias[c + 0], 0.f));
        h[1] = f2b(fmaxf(acc[cg][1] + bias[c + 1], 0.f));
        h[2] = f2b(fmaxf(acc[cg][2] + bias[c + 2], 0.f));
        h[3] = f2b(fmaxf(acc[cg][3] + bias[c + 3], 0.f));
        *(ushort4v*)&sm.pp.xls[mrow * 72 + c] = h;
        if (r < nrows) *(ushort4v*)&out[(size_t)r * 64 + c] = h;
    }
    __syncthreads();
    proj_phase<1>(sm.pp.xls, sm.pp.scratch, type, 0, w, lane, tid, r0b, nrows, Wpack, bpack, projAll);
}

// ---------------------------------------------------------------- epilogue (+ optional proj l+1), bf16 xs
template <int DO_PROJ>
__global__ __launch_bounds__(256) void epi_kernel(
    const float* __restrict__ agg0, const float* __restrict__ agg1,
    const ushort* __restrict__ WaPack, const float* __restrict__ ba,
    ushort* __restrict__ xs0, ushort* __restrict__ xs1,
    const float* __restrict__ skip, int l,
    const ushort* __restrict__ Wpack, const float* __restrict__ bpack,
    uchar* __restrict__ projAll)
{
    __shared__ ushort xls[DO_PROJ ? 128 * 72 : 64];
    __shared__ char scratch[DO_PROJ ? 16384 : 64];
    const int bx = blockIdx.x;
    const int type = (bx >= GB0) ? 1 : 0;
    const float* __restrict__ in = type ? agg1 : agg0;
    ushort* __restrict__ xs = type ? xs1 : xs0;
    const int nrows = type ? N1 : N0;
    const ushort* __restrict__ Wp = WaPack + (size_t)(l * 2 + type) * 4096;
    const float* __restrict__ bias = ba + (size_t)(l * 2 + type) * 64;
    const float beta = 1.f / (1.f + __expf(-skip[l * 2 + type]));

    const int tid = threadIdx.x, w = tid >> 6, lane = tid & 63;
    const int r0b = (type ? bx - GB0 : bx) * 128;
    const int r0 = r0b + w * 32;
    f32x4 acc[2][4] = {};
    #pragma unroll
    for (int ksp = 0; ksp < 2; ++ksp) {
        short8 bfr[2];
        #pragma unroll
        for (int rb = 0; rb < 2; ++rb) {
            int gr = min(r0 + rb * 16 + (lane & 15), nrows - 1);
            const float* src = in + (size_t)gr * 64 + ksp * 32 + (lane >> 4) * 8;
            float4 f0 = *(const float4*)src;
            float4 f1 = *(const float4*)(src + 4);
            short8 t;
            t[0] = (short)f2b(gelu_f(f0.x)); t[1] = (short)f2b(gelu_f(f0.y));
            t[2] = (short)f2b(gelu_f(f0.z)); t[3] = (short)f2b(gelu_f(f0.w));
            t[4] = (short)f2b(gelu_f(f1.x)); t[5] = (short)f2b(gelu_f(f1.y));
            t[6] = (short)f2b(gelu_f(f1.z)); t[7] = (short)f2b(gelu_f(f1.w));
            bfr[rb] = t;
        }
        const ushort* wb = Wp + ksp * 2048 + lane * 8;
        #pragma unroll
        for (int cg = 0; cg < 4; ++cg) {
            short8 afr = *(const short8*)&wb[cg * 512];
            acc[0][cg] = __builtin_amdgcn_mfma_f32_16x16x32_bf16(afr, bfr[0], acc[0][cg], 0, 0, 0);
            acc[1][cg] = __builtin_amdgcn_mfma_f32_16x16x32_bf16(afr, bfr[1], acc[1][cg], 0, 0, 0);
        }
    }
    const int c0b = (lane >> 4) * 4;
    #pragma unroll
    for (int rb = 0; rb < 2; ++rb) {
        int lrow = w * 32 + rb * 16 + (lane & 15);
        int r = r0b + lrow;
        int gr = min(r, nrows - 1);
        #pragma unroll
        for (int cg = 0; cg < 4; ++cg) {
            int c = cg * 16 + c0b;
            ushort4v xo = *(const ushort4v*)&xs[(size_t)gr * 64 + c];
            ushort4v h;
            h[0] = f2b(beta * (acc[rb][cg][0] + bias[c + 0]) + (1.f - beta) * b2f(xo[0]));
            h[1] = f2b(beta * (acc[rb][cg][1] + bias[c + 1]) + (1.f - beta) * b2f(xo[1]));
            h[2] = f2b(beta * (acc[rb][cg][2] + bias[c + 2]) + (1.f - beta) * b2f(xo[2]));
            h[3] = f2b(beta * (acc[rb][cg][3] + bias[c + 3]) + (1.f - beta) * b2f(xo[3]));
            if (DO_PROJ) *(ushort4v*)&xls[lrow * 72 + c] = h;
            if (r < nrows) *(ushort4v*)&xs[(size_t)r * 64 + c] = h;
        }
    }
    if (DO_PROJ) {
        __syncthreads();
        proj_phase<2>(xls, scratch, type, l + 1, w, lane, tid, r0b, nrows, Wpack, bpack, projAll);
    }
}

// ---------------------------------------------------------------- prep (fold + packs) + zero
__global__ __launch_bounds__(256) void prep_zero_kernel(
    const float* __restrict__ Wq, const float* __restrict__ bq,
    const float* __restrict__ Wk, const float* __restrict__ bk,
    const float* __restrict__ Wv, const float* __restrict__ bv,
    const float* __restrict__ Watt, const float* __restrict__ Wmsg,
    const float* __restrict__ prel, const float* __restrict__ Win,
    const float* __restrict__ Wa,
    ushort* __restrict__ Wpack, float* __restrict__ bpack,
    ushort* __restrict__ Wpin, ushort* __restrict__ WaPack,
    int* __restrict__ c0, int* __restrict__ c1,
    int* __restrict__ gs, int* __restrict__ gc)
{
    __shared__ float WF[4096];
    const int b = blockIdx.x;
    const int tid = threadIdx.x;
    if (b >= PREPB) {
        int i = (b - PREPB) * 256 + tid;
        if (i < N0) c0[i] = 0;
        else if (i < N0 + N1) c1[i - N0] = 0;
        else if (i < N0 + N1 + NG * 64) gs[i - N0 - N1] = 0;
        else if (i < N0 + N1 + NG * 64 + NG) gc[i - N0 - N1 - NG * 64] = 0;
        return;
    }
    if (b < 16) {
        const int l = b >> 3;
        const int slot = b & 7;
        const float SCALE = 0.17677669529663689f;  // 1/sqrt(32)
        ushort* outW = Wpack + (size_t)(l * 8 + slot) * 4096;
        float* outB = bpack + (size_t)(l * 8 + slot) * 64;
        const float *Wsrc = 0, *bsrc = 0, *A = 0, *prelE = 0;
        int copy = 0;
        switch (slot) {
            case 0: Wsrc = Wq + (l*2+0)*4096; bsrc = bq + (l*2+0)*64; copy = 1; break;
            case 5: Wsrc = Wq + (l*2+1)*4096; bsrc = bq + (l*2+1)*64; copy = 1; break;
            case 1: Wsrc = Wk + (l*2+0)*4096; bsrc = bk + (l*2+0)*64; A = Watt + (l*3+0)*2048; prelE = prel + l*6 + 0; break;
            case 2: Wsrc = Wv + (l*2+0)*4096; bsrc = bv + (l*2+0)*64; A = Wmsg + (l*3+0)*2048; break;
            case 3: Wsrc = Wk + (l*2+0)*4096; bsrc = bk + (l*2+0)*64; A = Watt + (l*3+2)*2048; prelE = prel + l*6 + 4; break;
            case 4: Wsrc = Wv + (l*2+0)*4096; bsrc = bv + (l*2+0)*64; A = Wmsg + (l*3+2)*2048; break;
            case 6: Wsrc = Wk + (l*2+1)*4096; bsrc = bk + (l*2+1)*64; A = Watt + (l*3+1)*2048; prelE = prel + l*6 + 2; break;
            case 7: Wsrc = Wv + (l*2+1)*4096; bsrc = bv + (l*2+1)*64; A = Wmsg + (l*3+1)*2048; break;
        }
        if (copy) {
            for (int idx = tid; idx < 4096; idx += 256) WF[idx] = Wsrc[idx];
            if (tid < 64) outB[tid] = bsrc[tid];
        } else {
            for (int idx = tid; idx < 4096; idx += 256) {
                int k = idx >> 6, c = idx & 63, h = c >> 5, f = c & 31;
                float s = 0.f;
                for (int d = 0; d < 32; ++d)
                    s += Wsrc[k * 64 + h * 32 + d] * A[(h * 32 + d) * 32 + f];
                if (prelE) s *= prelE[h] * SCALE;
                WF[idx] = s;
            }
            if (tid < 64) {
                int h = tid >> 5, f = tid & 31;
                float s = 0.f;
                for (int d = 0; d < 32; ++d)
                    s += bsrc[h * 32 + d] * A[(h * 32 + d) * 32 + f];
                if (prelE) s *= prelE[h] * SCALE;
                outB[tid] = s;
            }
        }
        __syncthreads();
        for (int idx = tid; idx < 4096; idx += 256) {
            int ksp = idx >> 11, rem = idx & 2047;
            int cg = rem >> 9, rem2 = rem & 511;
            int lane = rem2 >> 3, j = rem2 & 7;
            int k = ksp * 32 + (lane >> 4) * 8 + j;
            int c = cg * 16 + (lane & 15);
            outW[idx] = f2b(WF[k * 64 + c]);
        }
    } else if (b < 16 + 2 * KSTEPS_IN) {
        const int pb = b - 16;
        const int type = pb / KSTEPS_IN, ks = pb % KSTEPS_IN;
        const float* W = Win + (size_t)type * FIN * 64;
        ushort* out = Wpin + (size_t)pb * 2048;
        for (int idx = tid; idx < 2048; idx += 256) {
            int cg = idx >> 9, rem = idx & 511, lane = rem >> 3, j = rem & 7;
            int k = ks * 32 + (lane >> 4) * 8 + j;
            int c = cg * 16 + (lane & 15);
            out[idx] = f2b((k < FIN) ? W[(size_t)k * 64 + c] : 0.f);
        }
    } else {
        const int mb = b - 16 - 2 * KSTEPS_IN;
        const float* W = Wa + (size_t)mb * 4096;
        ushort* o = WaPack + (size_t)mb * 4096;
        for (int idx = tid; idx < 4096; idx += 256) {
            int ksp = idx >> 11, rem = idx & 2047;
            int cg = rem >> 9, rem2 = rem & 511;
            int lane = rem2 >> 3, j = rem2 & 7;
            int k = ksp * 32 + (lane >> 4) * 8 + j;
            int c = cg * 16 + (lane & 15);
            o[idx] = f2b(W[k * 64 + c]);
        }
    }
}

// ---------------------------------------------------------------- CSR build (vectorized)
__global__ void hist_all_kernel(
    const int* __restrict__ e0d, const int* __restrict__ e1d, const int* __restrict__ e2d,
    int* __restrict__ cnt0, int* __restrict__ cnt1)
{
    const int Q0 = E0N / 4, Q1 = E1N / 4, Q2 = E2N / 4;
    const int total = Q0 + Q1 + Q2;
    for (int i = blockIdx.x * blockDim.x + threadIdx.x; i < total; i += gridDim.x * blockDim.x) {
        int4 d;
        int* cnt;
        if (i < Q0) { d = *(const int4*)(e0d + i * 4); cnt = cnt0; }
        else if (i < Q0 + Q1) { d = *(const int4*)(e1d + (i - Q0) * 4); cnt = cnt0; }
        else { d = *(const int4*)(e2d + (i - Q0 - Q1) * 4); cnt = cnt1; }
        atomicAdd(&cnt[d.x], 1);
        atomicAdd(&cnt[d.y], 1);
        atomicAdd(&cnt[d.z], 1);
        atomicAdd(&cnt[d.w], 1);
    }
}

// scan1: per-1024-block exclusive offsets + RAW block sums; re-zeroes cnt.
__global__ __launch_bounds__(256) void scan1_all_kernel(
    int* __restrict__ cnt0, int* __restrict__ cnt1,
    int* __restrict__ off0, int* __restrict__ off1,
    int* __restrict__ bsA, int* __restrict__ bsB)
{
    __shared__ int sa[256], sb[256];
    const int tid = threadIdx.x;
    const int b = blockIdx.x;
    int* cnt; int n; int* off; int* bsum; int lb;
    if (b < SB0) { cnt = cnt0; n = N0; off = off0; bsum = bsA; lb = b; }
    else { cnt = cnt1; n = N1; off = off1; bsum = bsB; lb = b - SB0; }
    const int base = lb * 1024 + tid * 4;
    int v[4];
    int run = 0;
    #pragma unroll
    for (int i = 0; i < 4; ++i) {
        int x = (base + i < n) ? cnt[base + i] : 0;
        run += x; v[i] = run;
    }
    #pragma unroll
    for (int i = 0; i < 4; ++i)
        if (base + i < n) cnt[base + i] = 0;
    sa[tid] = run;
    __syncthreads();
    int* src = sa; int* dst = sb;
    for (int d = 1; d < 256; d <<= 1) {
        int x = src[tid];
        if (tid >= d) x += src[tid - d];
        dst[tid] = x;
        __syncthreads();
        int* t = src; src = dst; dst = t;
    }
    int excl = src[tid] - run;
    #pragma unroll
    for (int i = 0; i < 4; ++i)
        if (base + i < n) off[base + i + 1] = excl + v[i];
    if (tid == 255) bsum[lb] = src[255];   // RAW block total
}

// scan3: each block reduces raw block-sums [0, lb) itself (no scan2 kernel).
__global__ __launch_bounds__(256) void scan3_all_kernel(
    int* __restrict__ off0, int* __restrict__ off1,
    const int* __restrict__ bsA, const int* __restrict__ bsB)
{
    __shared__ int red[256];
    const int b = blockIdx.x;
    const int tid = threadIdx.x;
    int* off; const int* bsum; int n; int lb;
    if (b < SB0) { off = off0; bsum = bsA; n = N0; lb = b; }
    else { off = off1; bsum = bsB; n = N1; lb = b - SB0; }
    int partial = 0;
    for (int i = tid; i < lb; i += 256) partial += bsum[i];
    red[tid] = partial;
    __syncthreads();
    #pragma unroll
    for (int d = 128; d > 0; d >>= 1) {
        if (tid < d) red[tid] += red[tid + d];
        __syncthreads();
    }
    const int add = red[0];
    const int base = lb * 1024 + tid * 4;
    #pragma unroll
    for (int i = 0; i < 4; ++i)
        if (base + i < n) off[base + i + 1] += add;
    if (lb == 0 && tid == 0) off[0] = 0;
}

__global__ void scatter_all_kernel(
    const int* __restrict__ e0s, const int* __restrict__ e0d,
    const int* __restrict__ e1s, const int* __restrict__ e1d,
    const int* __restrict__ e2s, const int* __restrict__ e2d,
    const int* __restrict__ off0, const int* __restrict__ off1,
    int* __restrict__ cnt0, int* __restrict__ cnt1,
    int* __restrict__ rec0, int* __restrict__ rec1)
{
    const int Q0 = E0N / 4, Q1 = E1N / 4, Q2 = E2N / 4;
    const int total = Q0 + Q1 + Q2;
    for (int i = blockIdx.x * blockDim.x + threadIdx.x; i < total; i += gridDim.x * blockDim.x) {
        int4 d, sv;
        const int* off; int* cnt; int* rec; int tag;
        if (i < Q0) {
            d = *(const int4*)(e0d + i * 4); sv = *(const int4*)(e0s + i * 4);
            off = off0; cnt = cnt0; rec = rec0; tag = 0;
        } else if (i < Q0 + Q1) {
            int k = (i - Q0) * 4;
            d = *(const int4*)(e1d + k); sv = *(const int4*)(e1s + k);
            off = off0; cnt = cnt0; rec = rec0; tag = 1 << 20;
        } else {
            int k = (i - Q0 - Q1) * 4;
            d = *(const int4*)(e2d + k); sv = *(const int4*)(e2s + k);
            off = off1; cnt = cnt1; rec = rec1; tag = 0;
        }
        rec[off[d.x] + atomicAdd(&cnt[d.x], 1)] = sv.x | tag;
        rec[off[d.y] + atomicAdd(&cnt[d.y], 1)] = sv.y | tag;
        rec[off[d.z] + atomicAdd(&cnt[d.z], 1)] = sv.z | tag;
        rec[off[d.w] + atomicAdd(&cnt[d.w], 1)] = sv.w | tag;
    }
}

// ---------------------------------------------------------------- aggregation (fp8 KV, 16 edges/iter)
__global__ __launch_bounds__(256) void agg_fused(
    const int* __restrict__ off0, const int* __restrict__ rec0,
    const int* __restrict__ off1, const int* __restrict__ rec1,
    const uchar* __restrict__ projAll,
    float* __restrict__ agg0, float* __restrict__ agg1)
{
    const int bx = blockIdx.x;
    const int type = (bx >= AB0) ? 1 : 0;
    const int lane = threadIdx.x & 63;
    const int node = (type ? bx - AB0 : bx) * 4 + (threadIdx.x >> 6);
    const int ndst = type ? N1 : N0;
    if (node >= ndst) return;
    const int* __restrict__ off = type ? off1 : off0;
    const int* __restrict__ rec = type ? rec1 : rec0;
    const ushort* __restrict__ Q = (const ushort*)(projAll + (type ? Q1O : Q0O));
    const uchar* __restrict__ KVa = projAll + (type ? KV02O : KV00O);
    const uchar* __restrict__ KVb = projAll + (type ? KV02O : KV11O);
    float* __restrict__ outAgg = type ? agg1 : agg0;

    const int grp = lane >> 4;   // edge slot within group of 4
    const int gi  = lane & 15;   // dim-quad index
    float q0, q1, q2, q3;
    {
        const unsigned* qp = (const unsigned*)(Q + (size_t)node * 64 + gi * 4);
        unsigned u0 = qp[0], u1 = qp[1];
        q0 = lo16(u0) * INV_SKV; q1 = hi16(u0) * INV_SKV;
        q2 = lo16(u1) * INV_SKV; q3 = hi16(u1) * INV_SKV;
    }
    const int s = off[node], e = off[node + 1];
    float den = 0.f, a0 = 0.f, a1 = 0.f, a2 = 0.f, a3 = 0.f;
    for (int j = s; j < e; j += 16) {
        bool v[4]; uint2 kv[4]; float p[4];
        #pragma unroll
        for (int q = 0; q < 4; ++q) {
            int jj = j + grp + q * 4;
            v[q] = jj < e;
            int r = rec[v[q] ? jj : s];
            const uchar* KV = (r & (1 << 20)) ? KVb : KVa;
            kv[q] = *(const uint2*)(KV + ((size_t)(unsigned)(r & 0xFFFFF) << 7) + gi * 8);
        }
        #pragma unroll
        for (int q = 0; q < 4; ++q) {
            f32x2 kA = __builtin_amdgcn_cvt_pk_f32_fp8(kv[q].x, 0);
            f32x2 kB = __builtin_amdgcn_cvt_pk_f32_fp8(kv[q].x, 1);
            p[q] = kA[0] * q0 + kA[1] * q1 + kB[0] * q2 + kB[1] * q3;
        }
        #pragma unroll
        for (int q = 0; q < 4; ++q) p[q] += asf(__builtin_amdgcn_ds_swizzle(asi(p[q]), 0x041F));
        #pragma unroll
        for (int q = 0; q < 4; ++q) p[q] += asf(__builtin_amdgcn_ds_swizzle(asi(p[q]), 0x081F));
        #pragma unroll
        for (int q = 0; q < 4; ++q) p[q] += asf(__builtin_amdgcn_ds_swizzle(asi(p[q]), 0x101F));
        #pragma unroll
        for (int q = 0; q < 4; ++q) {
            float wgt = v[q] ? __expf(p[q]) : 0.f;
            den += wgt;
            f32x2 vA = __builtin_amdgcn_cvt_pk_f32_fp8(kv[q].y, 0);
            f32x2 vB = __builtin_amdgcn_cvt_pk_f32_fp8(kv[q].y, 1);
            a0 = fmaf(wgt, vA[0], a0);
            a1 = fmaf(wgt, vA[1], a1);
            a2 = fmaf(wgt, vB[0], a2);
            a3 = fmaf(wgt, vB[1], a3);
        }
    }
    a0 += __shfl_xor(a0, 16); a0 += __shfl_xor(a0, 32);
    a1 += __shfl_xor(a1, 16); a1 += __shfl_xor(a1, 32);
    a2 += __shfl_xor(a2, 16); a2 += __shfl_xor(a2, 32);
    a3 += __shfl_xor(a3, 16); a3 += __shfl_xor(a3, 32);
    den += __shfl_xor(den, 16); den += __shfl_xor(den, 32);
    if (lane < 16) {
        float inv = (den > 0.f) ? 1.f / (den * SKV) : 0.f;
        float4 o;
        o.x = a0 * inv; o.y = a1 * inv; o.z = a2 * inv; o.w = a3 * inv;
        *(float4*)&outAgg[(size_t)node * 64 + gi * 4] = o;
    }
}

// ---------------------------------------------------------------- segment mean (bf16 xs)
__global__ __launch_bounds__(256) void segsum_kernel(
    const ushort* __restrict__ xs, const int* __restrict__ seg, int n,
    float* __restrict__ gsum, int* __restrict__ gcnt)
{
    const int lane = threadIdx.x & 63;
    const int wid = blockIdx.x * 4 + (threadIdx.x >> 6);
    const int rbeg = wid * 256;
    if (rbeg >= n) return;
    const int rend = min(rbeg + 256, n);
    float s = 0.f;
    int cur = seg[rbeg];
    int run = 0;
    for (int r = rbeg; r < rend; ++r) {
        int sg = seg[r];
        if (sg != cur) {
            atomicAdd(&gsum[cur * 64 + lane], s);
            if (lane == 0) atomicAdd(&gcnt[cur], run);
            cur = sg; s = 0.f; run = 0;
        }
        s += b2f(xs[(size_t)r * 64 + lane]);
        run++;
    }
    atomicAdd(&gsum[cur * 64 + lane], s);
    if (lane == 0) atomicAdd(&gcnt[cur], run);
}

// ---------------------------------------------------------------- classifier head (1 block)
__global__ __launch_bounds__(256) void head_kernel(
    const float* __restrict__ gsum, const int* __restrict__ gcnt,
    const float* __restrict__ Wdeb, const float* __restrict__ bdeb,
    const float* __restrict__ Wvm, const float* __restrict__ bvm,
    const float* __restrict__ Wom, const float* __restrict__ bom,
    const float* __restrict__ Wc1, const float* __restrict__ bc1,
    const float* __restrict__ Wc2, const float* __restrict__ bc2,
    float* __restrict__ outp)
{
    __shared__ float A[4096], B[4096], C[4096];
    const int tid = threadIdx.x;
    for (int idx = tid; idx < 4096; idx += 256) {
        int g = idx >> 6;
        A[idx] = gsum[idx] / fmaxf((float)gcnt[g], 1.f);
    }
    __syncthreads();
    for (int idx = tid; idx < 4096; idx += 256) {
        int g = idx >> 6, c = idx & 63;
        float s = bdeb[c];
        for (int k = 0; k < 64; ++k) s = fmaf(A[g * 64 + k], Wdeb[k * 64 + c], s);
        B[idx] = s;
    }
    __syncthreads();
    for (int idx = tid; idx < 4096; idx += 256) {
        int g = idx >> 6, c = idx & 63;
        float s = bvm[c];
        for (int k = 0; k < 64; ++k) s = fmaf(B[g * 64 + k], Wvm[k * 64 + c], s);
        C[idx] = s;
    }
    __syncthreads();
    for (int idx = tid; idx < 4096; idx += 256) {
        int g = idx >> 6, c = idx & 63;
        float s = bom[c];
        for (int k = 0; k < 64; ++k) s = fmaf(C[g * 64 + k], Wom[k * 64 + c], s);
        A[idx] = s;
    }
    __syncthreads();
    for (int idx = tid; idx < 4096; idx += 256) {
        int g = idx >> 6, c = idx & 63;
        float s = bc1[c];
        for (int k = 0; k < 64; ++k) s = fmaf(B[g * 64 + k], Wc1[k * 64 + c], s);
        for (int k = 0; k < 64; ++k) s = fmaf(A[g * 64 + k], Wc1[(64 + k) * 64 + c], s);
        C[idx] = fmaxf(s, 0.f);
    }
    __syncthreads();
    if (tid < 64) {
        float s = bc2[0];
        for (int c = 0; c < 64; ++c) s = fmaf(C[tid * 64 + c], Wc2[c], s);
        outp[tid] = s;
    }
}

// ================================================================ launcher
extern "C" void kernel_launch(void* const* d_in, const int* in_sizes, int n_in,
                              void* d_out, int out_size, void* d_ws, size_t ws_size,
                              hipStream_t stream)
{
    const float* x_arg = (const float*)d_in[0];
    const float* x_ev  = (const float*)d_in[1];
    const float* Win   = (const float*)d_in[2];
    const float* b_in  = (const float*)d_in[3];
    const float* Wk    = (const float*)d_in[4];
    const float* bk    = (const float*)d_in[5];
    const float* Wq    = (const float*)d_in[6];
    const float* bq    = (const float*)d_in[7];
    const float* Wv    = (const float*)d_in[8];
    const float* bv    = (const float*)d_in[9];
    const float* Wa    = (const float*)d_in[10];
    const float* ba    = (const float*)d_in[11];
    const float* skip  = (const float*)d_in[12];
    const float* Watt  = (const float*)d_in[13];
    const float* Wmsg  = (const float*)d_in[14];
    const float* prel  = (const float*)d_in[15];
    const float* Wdeb  = (const float*)d_in[18];
    const float* bdeb  = (const float*)d_in[19];
    const float* Wvm   = (const float*)d_in[24];
    const float* bvm   = (const float*)d_in[25];
    const float* Wom   = (const float*)d_in[26];
    const float* bom   = (const float*)d_in[27];
    const float* Wc1   = (const float*)d_in[28];
    const float* bc1   = (const float*)d_in[29];
    const float* Wc2   = (const float*)d_in[30];
    const float* bc2   = (const float*)d_in[31];
    const int* e0s = (const int*)d_in[32];
    const int* e0d = (const int*)d_in[33];
    const int* e1s = (const int*)d_in[34];
    const int* e1d = (const int*)d_in[35];
    const int* e2s = (const int*)d_in[36];
    const int* e2d = (const int*)d_in[37];
    const int* batch = (const int*)d_in[38];
    float* outp = (float*)d_out;

    char* w = (char*)d_ws;
    size_t o = 0;
    auto alloc = [&](size_t bytes) -> char* {
        char* p = w + o;
        o = (o + bytes + 255) & ~(size_t)255;
        return p;
    };
    ushort* xs0  = (ushort*)alloc((size_t)N0 * 64 * 2);
    ushort* xs1  = (ushort*)alloc((size_t)N1 * 64 * 2);
    uchar* projAll = (uchar*)alloc((size_t)N0 * 384 + (size_t)N1 * 256);
    float* agg0  = (float*)alloc((size_t)N0 * 64 * 4);
    float* agg1  = (float*)alloc((size_t)N1 * 64 * 4);
    int* off0 = (int*)alloc((size_t)(N0 + 1) * 4);
    int* off1 = (int*)alloc((size_t)(N1 + 1) * 4);
    int* cnt0 = (int*)alloc((size_t)N0 * 4);
    int* cnt1 = (int*)alloc((size_t)N1 * 4);
    int* rec0 = (int*)alloc((size_t)(E0N + E1N) * 4);
    int* rec1 = (int*)alloc((size_t)E2N * 4);
    int* bsA  = (int*)alloc(256 * 4);
    int* bsB  = (int*)alloc(256 * 4);
    ushort* Wpack = (ushort*)alloc((size_t)16 * 4096 * 2);
    float* bpack = (float*)alloc((size_t)16 * 64 * 4);
    ushort* Wpin = (ushort*)alloc((size_t)2 * KSTEPS_IN * 2048 * 2);
    ushort* WaPack = (ushort*)alloc((size_t)4 * 4096 * 2);
    float* gsum = (float*)alloc((size_t)NG * 64 * 4);
    int* gcnt = (int*)alloc((size_t)NG * 4);
    if (o > ws_size) return;

    const int ZB = (N0 + N1 + NG * 64 + NG + 255) / 256;

    // 1. prep (fold + packs) + zero counters/pooling
    prep_zero_kernel<<<PREPB + ZB, 256, 0, stream>>>(
        Wq, bq, Wk, bk, Wv, bv, Watt, Wmsg, prel, Win, Wa,
        Wpack, bpack, Wpin, WaPack, cnt0, cnt1, (int*)gsum, gcnt);
    // 2. hist
    hist_all_kernel<<<1024, 256, 0, stream>>>(e0d, e1d, e2d, cnt0, cnt1);
    // 3-4. scans (scan2 folded into scan3)
    scan1_all_kernel<<<SB0 + SB1, 256, 0, stream>>>(cnt0, cnt1, off0, off1, bsA, bsB);
    scan3_all_kernel<<<SB0 + SB1, 256, 0, stream>>>(off0, off1, bsA, bsB);
    // 5. scatter
    scatter_all_kernel<<<1024, 256, 0, stream>>>(
        e0s, e0d, e1s, e1d, e2s, e2d, off0, off1, cnt0, cnt1, rec0, rec1);
    // 6. in_proj + proj l=0  (64-row linear-slab blocks)
    inproj_proj_kernel<<<GB064 + GB164, 256, 0, stream>>>(
        x_arg, x_ev, Wpin, b_in, xs0, xs1, Wpack, bpack, projAll);
    // 7. agg l=0
    agg_fused<<<AB0 + AB1, 256, 0, stream>>>(off0, rec0, off1, rec1, projAll, agg0, agg1);
    // 8. epi l=0 + proj l=1
    epi_kernel<1><<<GB0 + GB1, 256, 0, stream>>>(
        agg0, agg1, WaPack, ba, xs0, xs1, skip, 0, Wpack, bpack, projAll);
    // 9. agg l=1
    agg_fused<<<AB0 + AB1, 256, 0, stream>>>(off0, rec0, off1, rec1, projAll, agg0, agg1);
    // 10. epi l=1 (final)
    epi_kernel<0><<<GB0 + GB1, 256, 0, stream>>>(
        agg0, agg1, WaPack, ba, xs0, xs1, skip, 1, Wpack, bpack, projAll);
    // 11-12. pooling + head
    {
        int waves = (N0 + 255) / 256;
        segsum_kernel<<<(waves + 3) / 4, 256, 0, stream>>>(xs0, batch, N0, gsum, gcnt);
    }
    head_kernel<<<1, 256, 0, stream>>>(gsum, gcnt, Wdeb, bdeb, Wvm, bvm, Wom, bom,
                                       Wc1, bc1, Wc2, bc2, outp);
}

// Round 15
// 972.824 us; speedup vs baseline: 1.0690x; 1.0690x over previous
//
#include <hip/hip_runtime.h>
#include <math.h>

#define N0 120000
#define N1 60000
#define E0N 1500000
#define E1N 1000000
#define E2N 1000000
#define FIN 771
#define NG 64
#define KSTEPS_IN 25   // ceil(771/32)

#define GB0 ((N0 + 127) / 128)      // 938
#define GB1 ((N1 + 127) / 128)      // 469
#define AB0 ((N0 + 3) / 4)          // 30000
#define AB1 ((N1 + 3) / 4)          // 15000
#define SB0 ((N0 + 1023) / 1024)    // 118
#define SB1 ((N1 + 1023) / 1024)    // 59
#define PREPB 70                    // 16 fold + 50 win-pack + 4 wa-pack

// projAll BYTE offsets: all rows are 128 B.
#define Q0O   ((size_t)0)
#define KV00O ((size_t)N0 * 128)
#define KV02O ((size_t)N0 * 256)
#define Q1O   ((size_t)N0 * 384)
#define KV11O ((size_t)N0 * 384 + (size_t)N1 * 128)

#define SKV 256.0f            // fp8 pack scale for K and V
#define INV_SKV 0.00390625f

typedef __attribute__((ext_vector_type(8))) short short8;
typedef __attribute__((ext_vector_type(4))) float f32x4;
typedef __attribute__((ext_vector_type(2))) float f32x2;
typedef float f32x4u __attribute__((ext_vector_type(4), aligned(4)));
typedef __attribute__((ext_vector_type(4))) unsigned short ushort4v;
typedef unsigned short ushort;
typedef unsigned char uchar;

__device__ __forceinline__ float gelu_f(float v) {
    return 0.5f * v * (1.f + erff(v * 0.70710678118654752f));
}
__device__ __forceinline__ ushort f2b(float f) {
    union { float f; unsigned u; } v; v.f = f;
    unsigned u = v.u;
    return (ushort)((u + 0x7FFFu + ((u >> 16) & 1u)) >> 16);  // RNE
}
__device__ __forceinline__ float b2f(ushort h) {
    union { unsigned u; float f; } v; v.u = ((unsigned)h) << 16; return v.f;
}
__device__ __forceinline__ float lo16(unsigned u) {
    union { unsigned x; float f; } v; v.x = u << 16; return v.f;
}
__device__ __forceinline__ float hi16(unsigned u) {
    union { unsigned x; float f; } v; v.x = u & 0xFFFF0000u; return v.f;
}
__device__ __forceinline__ int asi(float f) { union { float f; int i; } v; v.f = f; return v.i; }
__device__ __forceinline__ float asf(int i) { union { int i; float f; } v; v.i = i; return v.f; }

// ---------------------------------------------------------------- proj phase
// xls: [128][72] bf16 xs rows. scratch: 16KB, XOR-swizzled [128][128B].
// Q rows: 64 bf16 (128B). KV rows: [16 quads][4 fp8 K | 4 fp8 V] (128B), scaled by SKV.
__device__ __forceinline__ void proj_phase(
    const ushort* xls, char* scratch, int type, int l, int w, int lane, int tid,
    int r0b, int nrows,
    const ushort* __restrict__ Wpack, const float* __restrict__ bpack,
    uchar* __restrict__ projAll)
{
    short8 bfr[2][2];
    #pragma unroll
    for (int ksp = 0; ksp < 2; ++ksp)
        #pragma unroll
        for (int rb = 0; rb < 2; ++rb)
            bfr[ksp][rb] = *(const short8*)&xls[(w * 32 + rb * 16 + (lane & 15)) * 72
                                                + ksp * 32 + (lane >> 4) * 8];
    const int sbase = l * 8 + (type ? 5 : 0);
    const int c0b = (lane >> 4) * 4;
    const int ngroups = type ? 2 : 3;

    for (int grp = 0; grp < ngroups; ++grp) {
        const int s0 = (grp == 0) ? 0 : (grp * 2 - 1);   // Q | (K1,V2) | (K3,V4)
        const int nsl = (grp == 0) ? 1 : 2;
        for (int si = 0; si < nsl; ++si) {
            const int slot = s0 + si;
            const ushort* Wp = Wpack + (size_t)(sbase + slot) * 4096;
            const float* bias = bpack + (size_t)(sbase + slot) * 64;
            f32x4 acc[2][4] = {};
            #pragma unroll
            for (int ksp = 0; ksp < 2; ++ksp) {
                const ushort* wb = Wp + ksp * 2048 + lane * 8;
                #pragma unroll
                for (int cg = 0; cg < 4; ++cg) {
                    short8 afr = *(const short8*)&wb[cg * 512];
                    acc[0][cg] = __builtin_amdgcn_mfma_f32_16x16x32_bf16(afr, bfr[ksp][0], acc[0][cg], 0, 0, 0);
                    acc[1][cg] = __builtin_amdgcn_mfma_f32_16x16x32_bf16(afr, bfr[ksp][1], acc[1][cg], 0, 0, 0);
                }
            }
            #pragma unroll
            for (int rb = 0; rb < 2; ++rb) {
                int lrow = w * 32 + rb * 16 + (lane & 15);
                const int sw = (lrow & 7) << 4;
                #pragma unroll
                for (int cg = 0; cg < 4; ++cg) {
                    int c = cg * 16 + c0b;
                    float v0 = acc[rb][cg][0] + bias[c + 0];
                    float v1 = acc[rb][cg][1] + bias[c + 1];
                    float v2 = acc[rb][cg][2] + bias[c + 2];
                    float v3 = acc[rb][cg][3] + bias[c + 3];
                    if (grp == 0) {
                        ushort4v o;
                        o[0] = f2b(v0); o[1] = f2b(v1); o[2] = f2b(v2); o[3] = f2b(v3);
                        *(ushort4v*)(scratch + lrow * 128 + ((c * 2) ^ sw)) = o;
                    } else {
                        int wrd = __builtin_amdgcn_cvt_pk_fp8_f32(v0 * SKV, v1 * SKV, 0, 0);
                        wrd = __builtin_amdgcn_cvt_pk_fp8_f32(v2 * SKV, v3 * SKV, wrd, 1);
                        *(int*)(scratch + lrow * 128 + ((((c >> 2) << 3) + (si << 2)) ^ sw)) = wrd;
                    }
                }
            }
        }
        __syncthreads();
        size_t ooff;
        if (grp == 0) ooff = type ? Q1O : Q0O;
        else if (grp == 1) ooff = type ? KV11O : KV00O;
        else ooff = KV02O;
        char* outg = (char*)projAll + ooff + (size_t)r0b * 128;
        #pragma unroll
        for (int q = 0; q < 4; ++q) {
            int off = q * 4096 + tid * 16;
            int row = off >> 7;
            int inner = off & 127;
            if (r0b + row < nrows)
                *(uint4*)(outg + off) =
                    *(const uint4*)(scratch + row * 128 + (inner ^ ((row & 7) << 4)));
        }
        __syncthreads();
    }
}

// ---------------------------------------------------------------- in_proj + proj l=0 (bf16 xs out)
__global__ __launch_bounds__(256) void inproj_proj_kernel(
    const float* __restrict__ xa, const float* __restrict__ xe,
    const ushort* __restrict__ Wpin, const float* __restrict__ b_in,
    ushort* __restrict__ xs0, ushort* __restrict__ xs1,
    const ushort* __restrict__ Wpack, const float* __restrict__ bpack,
    uchar* __restrict__ projAll)
{
    __shared__ ushort xls[128 * 72];
    __shared__ char scratch[16384];
    const int bx = blockIdx.x;
    const int type = (bx >= GB0) ? 1 : 0;
    const float* __restrict__ x = type ? xe : xa;
    const int nrows = type ? N1 : N0;
    const ushort* __restrict__ Wp = Wpin + (type ? (size_t)KSTEPS_IN * 2048 : 0);
    const float* __restrict__ bias = b_in + type * 64;
    ushort* __restrict__ out = type ? xs1 : xs0;

    const int tid = threadIdx.x, w = tid >> 6, lane = tid & 63;
    const int r0b = (type ? bx - GB0 : bx) * 128;

    const int rA = min(r0b + w * 32 + (lane & 15), nrows - 1);
    const int rB = min(r0b + w * 32 + 16 + (lane & 15), nrows - 1);
    const float* __restrict__ xA = x + (size_t)rA * FIN + (lane >> 4) * 8;
    const float* __restrict__ xB = x + (size_t)rB * FIN + (lane >> 4) * 8;

    f32x4 acc[2][4] = {};
    f32x4u cb[3][4];
    cb[0][0] = *(const f32x4u*)xA;        cb[0][1] = *(const f32x4u*)(xA + 4);
    cb[0][2] = *(const f32x4u*)xB;        cb[0][3] = *(const f32x4u*)(xB + 4);
    cb[1][0] = *(const f32x4u*)(xA + 32); cb[1][1] = *(const f32x4u*)(xA + 36);
    cb[1][2] = *(const f32x4u*)(xB + 32); cb[1][3] = *(const f32x4u*)(xB + 36);

    #pragma unroll
    for (int ks = 0; ks < 24; ++ks) {
        if (ks + 2 < 24) {
            const float* pA = xA + (ks + 2) * 32;
            const float* pB = xB + (ks + 2) * 32;
            cb[(ks + 2) % 3][0] = *(const f32x4u*)pA;
            cb[(ks + 2) % 3][1] = *(const f32x4u*)(pA + 4);
            cb[(ks + 2) % 3][2] = *(const f32x4u*)pB;
            cb[(ks + 2) % 3][3] = *(const f32x4u*)(pB + 4);
        }
        const int cur = ks % 3;
        short8 bA, bB;
        #pragma unroll
        for (int j = 0; j < 4; ++j) {
            bA[j]     = (short)f2b(cb[cur][0][j]);
            bA[j + 4] = (short)f2b(cb[cur][1][j]);
            bB[j]     = (short)f2b(cb[cur][2][j]);
            bB[j + 4] = (short)f2b(cb[cur][3][j]);
        }
        const ushort* wb = Wp + (size_t)ks * 2048 + lane * 8;
        #pragma unroll
        for (int cg = 0; cg < 4; ++cg) {
            short8 afr = *(const short8*)&wb[cg * 512];
            acc[0][cg] = __builtin_amdgcn_mfma_f32_16x16x32_bf16(afr, bA, acc[0][cg], 0, 0, 0);
            acc[1][cg] = __builtin_amdgcn_mfma_f32_16x16x32_bf16(afr, bB, acc[1][cg], 0, 0, 0);
        }
    }
    // tail k-step (k = 768..770, only frag group 0, j<3)
    {
        short8 bA = {}, bB = {};
        if ((lane >> 4) == 0) {
            const float* tA = x + (size_t)rA * FIN + 768;
            const float* tB = x + (size_t)rB * FIN + 768;
            bA[0] = (short)f2b(tA[0]); bA[1] = (short)f2b(tA[1]); bA[2] = (short)f2b(tA[2]);
            bB[0] = (short)f2b(tB[0]); bB[1] = (short)f2b(tB[1]); bB[2] = (short)f2b(tB[2]);
        }
        const ushort* wb = Wp + (size_t)24 * 2048 + lane * 8;
        #pragma unroll
        for (int cg = 0; cg < 4; ++cg) {
            short8 afr = *(const short8*)&wb[cg * 512];
            acc[0][cg] = __builtin_amdgcn_mfma_f32_16x16x32_bf16(afr, bA, acc[0][cg], 0, 0, 0);
            acc[1][cg] = __builtin_amdgcn_mfma_f32_16x16x32_bf16(afr, bB, acc[1][cg], 0, 0, 0);
        }
    }
    const int c0b = (lane >> 4) * 4;
    #pragma unroll
    for (int rb = 0; rb < 2; ++rb) {
        int lrow = w * 32 + rb * 16 + (lane & 15);
        int r = r0b + lrow;
        #pragma unroll
        for (int cg = 0; cg < 4; ++cg) {
            int c = cg * 16 + c0b;
            ushort4v h;
            h[0] = f2b(fmaxf(acc[rb][cg][0] + bias[c + 0], 0.f));
            h[1] = f2b(fmaxf(acc[rb][cg][1] + bias[c + 1], 0.f));
            h[2] = f2b(fmaxf(acc[rb][cg][2] + bias[c + 2], 0.f));
            h[3] = f2b(fmaxf(acc[rb][cg][3] + bias[c + 3], 0.f));
            *(ushort4v*)&xls[lrow * 72 + c] = h;
            if (r < nrows) *(ushort4v*)&out[(size_t)r * 64 + c] = h;
        }
    }
    __syncthreads();
    proj_phase(xls, scratch, type, 0, w, lane, tid, r0b, nrows, Wpack, bpack, projAll);
}

// ---------------------------------------------------------------- epilogue (+ optional proj l+1), bf16 xs
template <int DO_PROJ>
__global__ __launch_bounds__(256) void epi_kernel(
    const float* __restrict__ agg0, const float* __restrict__ agg1,
    const ushort* __restrict__ WaPack, const float* __restrict__ ba,
    ushort* __restrict__ xs0, ushort* __restrict__ xs1,
    const float* __restrict__ skip, int l,
    const ushort* __restrict__ Wpack, const float* __restrict__ bpack,
    uchar* __restrict__ projAll)
{
    __shared__ ushort xls[DO_PROJ ? 128 * 72 : 64];
    __shared__ char scratch[DO_PROJ ? 16384 : 64];
    const int bx = blockIdx.x;
    const int type = (bx >= GB0) ? 1 : 0;
    const float* __restrict__ in = type ? agg1 : agg0;
    ushort* __restrict__ xs = type ? xs1 : xs0;
    const int nrows = type ? N1 : N0;
    const ushort* __restrict__ Wp = WaPack + (size_t)(l * 2 + type) * 4096;
    const float* __restrict__ bias = ba + (size_t)(l * 2 + type) * 64;
    const float beta = 1.f / (1.f + __expf(-skip[l * 2 + type]));

    const int tid = threadIdx.x, w = tid >> 6, lane = tid & 63;
    const int r0b = (type ? bx - GB0 : bx) * 128;
    const int r0 = r0b + w * 32;
    f32x4 acc[2][4] = {};
    #pragma unroll
    for (int ksp = 0; ksp < 2; ++ksp) {
        short8 bfr[2];
        #pragma unroll
        for (int rb = 0; rb < 2; ++rb) {
            int gr = min(r0 + rb * 16 + (lane & 15), nrows - 1);
            const float* src = in + (size_t)gr * 64 + ksp * 32 + (lane >> 4) * 8;
            float4 f0 = *(const float4*)src;
            float4 f1 = *(const float4*)(src + 4);
            short8 t;
            t[0] = (short)f2b(gelu_f(f0.x)); t[1] = (short)f2b(gelu_f(f0.y));
            t[2] = (short)f2b(gelu_f(f0.z)); t[3] = (short)f2b(gelu_f(f0.w));
            t[4] = (short)f2b(gelu_f(f1.x)); t[5] = (short)f2b(gelu_f(f1.y));
            t[6] = (short)f2b(gelu_f(f1.z)); t[7] = (short)f2b(gelu_f(f1.w));
            bfr[rb] = t;
        }
        const ushort* wb = Wp + ksp * 2048 + lane * 8;
        #pragma unroll
        for (int cg = 0; cg < 4; ++cg) {
            short8 afr = *(const short8*)&wb[cg * 512];
            acc[0][cg] = __builtin_amdgcn_mfma_f32_16x16x32_bf16(afr, bfr[0], acc[0][cg], 0, 0, 0);
            acc[1][cg] = __builtin_amdgcn_mfma_f32_16x16x32_bf16(afr, bfr[1], acc[1][cg], 0, 0, 0);
        }
    }
    const int c0b = (lane >> 4) * 4;
    #pragma unroll
    for (int rb = 0; rb < 2; ++rb) {
        int lrow = w * 32 + rb * 16 + (lane & 15);
        int r = r0b + lrow;
        int gr = min(r, nrows - 1);
        #pragma unroll
        for (int cg = 0; cg < 4; ++cg) {
            int c = cg * 16 + c0b;
            ushort4v xo = *(const ushort4v*)&xs[(size_t)gr * 64 + c];
            ushort4v h;
            h[0] = f2b(beta * (acc[rb][cg][0] + bias[c + 0]) + (1.f - beta) * b2f(xo[0]));
            h[1] = f2b(beta * (acc[rb][cg][1] + bias[c + 1]) + (1.f - beta) * b2f(xo[1]));
            h[2] = f2b(beta * (acc[rb][cg][2] + bias[c + 2]) + (1.f - beta) * b2f(xo[2]));
            h[3] = f2b(beta * (acc[rb][cg][3] + bias[c + 3]) + (1.f - beta) * b2f(xo[3]));
            if (DO_PROJ) *(ushort4v*)&xls[lrow * 72 + c] = h;
            if (r < nrows) *(ushort4v*)&xs[(size_t)r * 64 + c] = h;
        }
    }
    if (DO_PROJ) {
        __syncthreads();
        proj_phase(xls, scratch, type, l + 1, w, lane, tid, r0b, nrows, Wpack, bpack, projAll);
    }
}

// ---------------------------------------------------------------- prep (fold + packs) + zero
__global__ __launch_bounds__(256) void prep_zero_kernel(
    const float* __restrict__ Wq, const float* __restrict__ bq,
    const float* __restrict__ Wk, const float* __restrict__ bk,
    const float* __restrict__ Wv, const float* __restrict__ bv,
    const float* __restrict__ Watt, const float* __restrict__ Wmsg,
    const float* __restrict__ prel, const float* __restrict__ Win,
    const float* __restrict__ Wa,
    ushort* __restrict__ Wpack, float* __restrict__ bpack,
    ushort* __restrict__ Wpin, ushort* __restrict__ WaPack,
    int* __restrict__ c0, int* __restrict__ c1,
    int* __restrict__ gs, int* __restrict__ gc)
{
    __shared__ float WF[4096];
    const int b = blockIdx.x;
    const int tid = threadIdx.x;
    if (b >= PREPB) {
        int i = (b - PREPB) * 256 + tid;
        if (i < N0) c0[i] = 0;
        else if (i < N0 + N1) c1[i - N0] = 0;
        else if (i < N0 + N1 + NG * 64) gs[i - N0 - N1] = 0;
        else if (i < N0 + N1 + NG * 64 + NG) gc[i - N0 - N1 - NG * 64] = 0;
        return;
    }
    if (b < 16) {
        const int l = b >> 3;
        const int slot = b & 7;
        const float SCALE = 0.17677669529663689f;  // 1/sqrt(32)
        ushort* outW = Wpack + (size_t)(l * 8 + slot) * 4096;
        float* outB = bpack + (size_t)(l * 8 + slot) * 64;
        const float *Wsrc = 0, *bsrc = 0, *A = 0, *prelE = 0;
        int copy = 0;
        switch (slot) {
            case 0: Wsrc = Wq + (l*2+0)*4096; bsrc = bq + (l*2+0)*64; copy = 1; break;
            case 5: Wsrc = Wq + (l*2+1)*4096; bsrc = bq + (l*2+1)*64; copy = 1; break;
            case 1: Wsrc = Wk + (l*2+0)*4096; bsrc = bk + (l*2+0)*64; A = Watt + (l*3+0)*2048; prelE = prel + l*6 + 0; break;
            case 2: Wsrc = Wv + (l*2+0)*4096; bsrc = bv + (l*2+0)*64; A = Wmsg + (l*3+0)*2048; break;
            case 3: Wsrc = Wk + (l*2+0)*4096; bsrc = bk + (l*2+0)*64; A = Watt + (l*3+2)*2048; prelE = prel + l*6 + 4; break;
            case 4: Wsrc = Wv + (l*2+0)*4096; bsrc = bv + (l*2+0)*64; A = Wmsg + (l*3+2)*2048; break;
            case 6: Wsrc = Wk + (l*2+1)*4096; bsrc = bk + (l*2+1)*64; A = Watt + (l*3+1)*2048; prelE = prel + l*6 + 2; break;
            case 7: Wsrc = Wv + (l*2+1)*4096; bsrc = bv + (l*2+1)*64; A = Wmsg + (l*3+1)*2048; break;
        }
        if (copy) {
            for (int idx = tid; idx < 4096; idx += 256) WF[idx] = Wsrc[idx];
            if (tid < 64) outB[tid] = bsrc[tid];
        } else {
            for (int idx = tid; idx < 4096; idx += 256) {
                int k = idx >> 6, c = idx & 63, h = c >> 5, f = c & 31;
                float s = 0.f;
                for (int d = 0; d < 32; ++d)
                    s += Wsrc[k * 64 + h * 32 + d] * A[(h * 32 + d) * 32 + f];
                if (prelE) s *= prelE[h] * SCALE;
                WF[idx] = s;
            }
            if (tid < 64) {
                int h = tid >> 5, f = tid & 31;
                float s = 0.f;
                for (int d = 0; d < 32; ++d)
                    s += bsrc[h * 32 + d] * A[(h * 32 + d) * 32 + f];
                if (prelE) s *= prelE[h] * SCALE;
                outB[tid] = s;
            }
        }
        __syncthreads();
        for (int idx = tid; idx < 4096; idx += 256) {
            int ksp = idx >> 11, rem = idx & 2047;
            int cg = rem >> 9, rem2 = rem & 511;
            int lane = rem2 >> 3, j = rem2 & 7;
            int k = ksp * 32 + (lane >> 4) * 8 + j;
            int c = cg * 16 + (lane & 15);
            outW[idx] = f2b(WF[k * 64 + c]);
        }
    } else if (b < 16 + 2 * KSTEPS_IN) {
        const int pb = b - 16;
        const int type = pb / KSTEPS_IN, ks = pb % KSTEPS_IN;
        const float* W = Win + (size_t)type * FIN * 64;
        ushort* out = Wpin + (size_t)pb * 2048;
        for (int idx = tid; idx < 2048; idx += 256) {
            int cg = idx >> 9, rem = idx & 511, lane = rem >> 3, j = rem & 7;
            int k = ks * 32 + (lane >> 4) * 8 + j;
            int c = cg * 16 + (lane & 15);
            out[idx] = f2b((k < FIN) ? W[(size_t)k * 64 + c] : 0.f);
        }
    } else {
        const int mb = b - 16 - 2 * KSTEPS_IN;
        const float* W = Wa + (size_t)mb * 4096;
        ushort* o = WaPack + (size_t)mb * 4096;
        for (int idx = tid; idx < 4096; idx += 256) {
            int ksp = idx >> 11, rem = idx & 2047;
            int cg = rem >> 9, rem2 = rem & 511;
            int lane = rem2 >> 3, j = rem2 & 7;
            int k = ksp * 32 + (lane >> 4) * 8 + j;
            int c = cg * 16 + (lane & 15);
            o[idx] = f2b(W[k * 64 + c]);
        }
    }
}

// ---------------------------------------------------------------- CSR build (vectorized)
__global__ void hist_all_kernel(
    const int* __restrict__ e0d, const int* __restrict__ e1d, const int* __restrict__ e2d,
    int* __restrict__ cnt0, int* __restrict__ cnt1)
{
    const int Q0 = E0N / 4, Q1 = E1N / 4, Q2 = E2N / 4;
    const int total = Q0 + Q1 + Q2;
    for (int i = blockIdx.x * blockDim.x + threadIdx.x; i < total; i += gridDim.x * blockDim.x) {
        int4 d;
        int* cnt;
        if (i < Q0) { d = *(const int4*)(e0d + i * 4); cnt = cnt0; }
        else if (i < Q0 + Q1) { d = *(const int4*)(e1d + (i - Q0) * 4); cnt = cnt0; }
        else { d = *(const int4*)(e2d + (i - Q0 - Q1) * 4); cnt = cnt1; }
        atomicAdd(&cnt[d.x], 1);
        atomicAdd(&cnt[d.y], 1);
        atomicAdd(&cnt[d.z], 1);
        atomicAdd(&cnt[d.w], 1);
    }
}

// scan1: per-1024-block exclusive offsets + RAW block sums; re-zeroes cnt.
__global__ __launch_bounds__(256) void scan1_all_kernel(
    int* __restrict__ cnt0, int* __restrict__ cnt1,
    int* __restrict__ off0, int* __restrict__ off1,
    int* __restrict__ bsA, int* __restrict__ bsB)
{
    __shared__ int sa[256], sb[256];
    const int tid = threadIdx.x;
    const int b = blockIdx.x;
    int* cnt; int n; int* off; int* bsum; int lb;
    if (b < SB0) { cnt = cnt0; n = N0; off = off0; bsum = bsA; lb = b; }
    else { cnt = cnt1; n = N1; off = off1; bsum = bsB; lb = b - SB0; }
    const int base = lb * 1024 + tid * 4;
    int v[4];
    int run = 0;
    #pragma unroll
    for (int i = 0; i < 4; ++i) {
        int x = (base + i < n) ? cnt[base + i] : 0;
        run += x; v[i] = run;
    }
    #pragma unroll
    for (int i = 0; i < 4; ++i)
        if (base + i < n) cnt[base + i] = 0;
    sa[tid] = run;
    __syncthreads();
    int* src = sa; int* dst = sb;
    for (int d = 1; d < 256; d <<= 1) {
        int x = src[tid];
        if (tid >= d) x += src[tid - d];
        dst[tid] = x;
        __syncthreads();
        int* t = src; src = dst; dst = t;
    }
    int excl = src[tid] - run;
    #pragma unroll
    for (int i = 0; i < 4; ++i)
        if (base + i < n) off[base + i + 1] = excl + v[i];
    if (tid == 255) bsum[lb] = src[255];   // RAW block total
}

// scan3: each block reduces raw block-sums [0, lb) itself (no scan2 kernel).
__global__ __launch_bounds__(256) void scan3_all_kernel(
    int* __restrict__ off0, int* __restrict__ off1,
    const int* __restrict__ bsA, const int* __restrict__ bsB)
{
    __shared__ int red[256];
    const int b = blockIdx.x;
    const int tid = threadIdx.x;
    int* off; const int* bsum; int n; int lb;
    if (b < SB0) { off = off0; bsum = bsA; n = N0; lb = b; }
    else { off = off1; bsum = bsB; n = N1; lb = b - SB0; }
    int partial = 0;
    for (int i = tid; i < lb; i += 256) partial += bsum[i];
    red[tid] = partial;
    __syncthreads();
    #pragma unroll
    for (int d = 128; d > 0; d >>= 1) {
        if (tid < d) red[tid] += red[tid + d];
        __syncthreads();
    }
    const int add = red[0];
    const int base = lb * 1024 + tid * 4;
    #pragma unroll
    for (int i = 0; i < 4; ++i)
        if (base + i < n) off[base + i + 1] += add;
    if (lb == 0 && tid == 0) off[0] = 0;
}

__global__ void scatter_all_kernel(
    const int* __restrict__ e0s, const int* __restrict__ e0d,
    const int* __restrict__ e1s, const int* __restrict__ e1d,
    const int* __restrict__ e2s, const int* __restrict__ e2d,
    const int* __restrict__ off0, const int* __restrict__ off1,
    int* __restrict__ cnt0, int* __restrict__ cnt1,
    int* __restrict__ rec0, int* __restrict__ rec1)
{
    const int Q0 = E0N / 4, Q1 = E1N / 4, Q2 = E2N / 4;
    const int total = Q0 + Q1 + Q2;
    for (int i = blockIdx.x * blockDim.x + threadIdx.x; i < total; i += gridDim.x * blockDim.x) {
        int4 d, sv;
        const int* off; int* cnt; int* rec; int tag;
        if (i < Q0) {
            d = *(const int4*)(e0d + i * 4); sv = *(const int4*)(e0s + i * 4);
            off = off0; cnt = cnt0; rec = rec0; tag = 0;
        } else if (i < Q0 + Q1) {
            int k = (i - Q0) * 4;
            d = *(const int4*)(e1d + k); sv = *(const int4*)(e1s + k);
            off = off0; cnt = cnt0; rec = rec0; tag = 1 << 20;
        } else {
            int k = (i - Q0 - Q1) * 4;
            d = *(const int4*)(e2d + k); sv = *(const int4*)(e2s + k);
            off = off1; cnt = cnt1; rec = rec1; tag = 0;
        }
        rec[off[d.x] + atomicAdd(&cnt[d.x], 1)] = sv.x | tag;
        rec[off[d.y] + atomicAdd(&cnt[d.y], 1)] = sv.y | tag;
        rec[off[d.z] + atomicAdd(&cnt[d.z], 1)] = sv.z | tag;
        rec[off[d.w] + atomicAdd(&cnt[d.w], 1)] = sv.w | tag;
    }
}

// ---------------------------------------------------------------- aggregation (fp8 KV, 16 edges/iter)
__global__ __launch_bounds__(256) void agg_fused(
    const int* __restrict__ off0, const int* __restrict__ rec0,
    const int* __restrict__ off1, const int* __restrict__ rec1,
    const uchar* __restrict__ projAll,
    float* __restrict__ agg0, float* __restrict__ agg1)
{
    const int bx = blockIdx.x;
    const int type = (bx >= AB0) ? 1 : 0;
    const int lane = threadIdx.x & 63;
    const int node = (type ? bx - AB0 : bx) * 4 + (threadIdx.x >> 6);
    const int ndst = type ? N1 : N0;
    if (node >= ndst) return;
    const int* __restrict__ off = type ? off1 : off0;
    const int* __restrict__ rec = type ? rec1 : rec0;
    const ushort* __restrict__ Q = (const ushort*)(projAll + (type ? Q1O : Q0O));
    const uchar* __restrict__ KVa = projAll + (type ? KV02O : KV00O);
    const uchar* __restrict__ KVb = projAll + (type ? KV02O : KV11O);
    float* __restrict__ outAgg = type ? agg1 : agg0;

    const int grp = lane >> 4;   // edge slot within group of 4
    const int gi  = lane & 15;   // dim-quad index
    float q0, q1, q2, q3;
    {
        const unsigned* qp = (const unsigned*)(Q + (size_t)node * 64 + gi * 4);
        unsigned u0 = qp[0], u1 = qp[1];
        q0 = lo16(u0) * INV_SKV; q1 = hi16(u0) * INV_SKV;
        q2 = lo16(u1) * INV_SKV; q3 = hi16(u1) * INV_SKV;
    }
    const int s = off[node], e = off[node + 1];
    float den = 0.f, a0 = 0.f, a1 = 0.f, a2 = 0.f, a3 = 0.f;
    for (int j = s; j < e; j += 16) {
        bool v[4]; uint2 kv[4]; float p[4];
        #pragma unroll
        for (int q = 0; q < 4; ++q) {
            int jj = j + grp + q * 4;
            v[q] = jj < e;
            int r = rec[v[q] ? jj : s];
            const uchar* KV = (r & (1 << 20)) ? KVb : KVa;
            kv[q] = *(const uint2*)(KV + ((size_t)(unsigned)(r & 0xFFFFF) << 7) + gi * 8);
        }
        #pragma unroll
        for (int q = 0; q < 4; ++q) {
            f32x2 kA = __builtin_amdgcn_cvt_pk_f32_fp8(kv[q].x, 0);
            f32x2 kB = __builtin_amdgcn_cvt_pk_f32_fp8(kv[q].x, 1);
            p[q] = kA[0] * q0 + kA[1] * q1 + kB[0] * q2 + kB[1] * q3;
        }
        #pragma unroll
        for (int q = 0; q < 4; ++q) p[q] += asf(__builtin_amdgcn_ds_swizzle(asi(p[q]), 0x041F));
        #pragma unroll
        for (int q = 0; q < 4; ++q) p[q] += asf(__builtin_amdgcn_ds_swizzle(asi(p[q]), 0x081F));
        #pragma unroll
        for (int q = 0; q < 4; ++q) p[q] += asf(__builtin_amdgcn_ds_swizzle(asi(p[q]), 0x101F));
        #pragma unroll
        for (int q = 0; q < 4; ++q) {
            float wgt = v[q] ? __expf(p[q]) : 0.f;
            den += wgt;
            f32x2 vA = __builtin_amdgcn_cvt_pk_f32_fp8(kv[q].y, 0);
            f32x2 vB = __builtin_amdgcn_cvt_pk_f32_fp8(kv[q].y, 1);
            a0 = fmaf(wgt, vA[0], a0);
            a1 = fmaf(wgt, vA[1], a1);
            a2 = fmaf(wgt, vB[0], a2);
            a3 = fmaf(wgt, vB[1], a3);
        }
    }
    a0 += __shfl_xor(a0, 16); a0 += __shfl_xor(a0, 32);
    a1 += __shfl_xor(a1, 16); a1 += __shfl_xor(a1, 32);
    a2 += __shfl_xor(a2, 16); a2 += __shfl_xor(a2, 32);
    a3 += __shfl_xor(a3, 16); a3 += __shfl_xor(a3, 32);
    den += __shfl_xor(den, 16); den += __shfl_xor(den, 32);
    if (lane < 16) {
        float inv = (den > 0.f) ? 1.f / (den * SKV) : 0.f;
        float4 o;
        o.x = a0 * inv; o.y = a1 * inv; o.z = a2 * inv; o.w = a3 * inv;
        *(float4*)&outAgg[(size_t)node * 64 + gi * 4] = o;
    }
}

// ---------------------------------------------------------------- segment mean (bf16 xs)
__global__ __launch_bounds__(256) void segsum_kernel(
    const ushort* __restrict__ xs, const int* __restrict__ seg, int n,
    float* __restrict__ gsum, int* __restrict__ gcnt)
{
    const int lane = threadIdx.x & 63;
    const int wid = blockIdx.x * 4 + (threadIdx.x >> 6);
    const int rbeg = wid * 256;
    if (rbeg >= n) return;
    const int rend = min(rbeg + 256, n);
    float s = 0.f;
    int cur = seg[rbeg];
    int run = 0;
    for (int r = rbeg; r < rend; ++r) {
        int sg = seg[r];
        if (sg != cur) {
            atomicAdd(&gsum[cur * 64 + lane], s);
            if (lane == 0) atomicAdd(&gcnt[cur], run);
            cur = sg; s = 0.f; run = 0;
        }
        s += b2f(xs[(size_t)r * 64 + lane]);
        run++;
    }
    atomicAdd(&gsum[cur * 64 + lane], s);
    if (lane == 0) atomicAdd(&gcnt[cur], run);
}

// ---------------------------------------------------------------- classifier head (1 block)
__global__ __launch_bounds__(256) void head_kernel(
    const float* __restrict__ gsum, const int* __restrict__ gcnt,
    const float* __restrict__ Wdeb, const float* __restrict__ bdeb,
    const float* __restrict__ Wvm, const float* __restrict__ bvm,
    const float* __restrict__ Wom, const float* __restrict__ bom,
    const float* __restrict__ Wc1, const float* __restrict__ bc1,
    const float* __restrict__ Wc2, const float* __restrict__ bc2,
    float* __restrict__ outp)
{
    __shared__ float A[4096], B[4096], C[4096];
    const int tid = threadIdx.x;
    for (int idx = tid; idx < 4096; idx += 256) {
        int g = idx >> 6;
        A[idx] = gsum[idx] / fmaxf((float)gcnt[g], 1.f);
    }
    __syncthreads();
    for (int idx = tid; idx < 4096; idx += 256) {
        int g = idx >> 6, c = idx & 63;
        float s = bdeb[c];
        for (int k = 0; k < 64; ++k) s = fmaf(A[g * 64 + k], Wdeb[k * 64 + c], s);
        B[idx] = s;
    }
    __syncthreads();
    for (int idx = tid; idx < 4096; idx += 256) {
        int g = idx >> 6, c = idx & 63;
        float s = bvm[c];
        for (int k = 0; k < 64; ++k) s = fmaf(B[g * 64 + k], Wvm[k * 64 + c], s);
        C[idx] = s;
    }
    __syncthreads();
    for (int idx = tid; idx < 4096; idx += 256) {
        int g = idx >> 6, c = idx & 63;
        float s = bom[c];
        for (int k = 0; k < 64; ++k) s = fmaf(C[g * 64 + k], Wom[k * 64 + c], s);
        A[idx] = s;
    }
    __syncthreads();
    for (int idx = tid; idx < 4096; idx += 256) {
        int g = idx >> 6, c = idx & 63;
        float s = bc1[c];
        for (int k = 0; k < 64; ++k) s = fmaf(B[g * 64 + k], Wc1[k * 64 + c], s);
        for (int k = 0; k < 64; ++k) s = fmaf(A[g * 64 + k], Wc1[(64 + k) * 64 + c], s);
        C[idx] = fmaxf(s, 0.f);
    }
    __syncthreads();
    if (tid < 64) {
        float s = bc2[0];
        for (int c = 0; c < 64; ++c) s = fmaf(C[tid * 64 + c], Wc2[c], s);
        outp[tid] = s;
    }
}

// ================================================================ launcher
extern "C" void kernel_launch(void* const* d_in, const int* in_sizes, int n_in,
                              void* d_out, int out_size, void* d_ws, size_t ws_size,
                              hipStream_t stream)
{
    const float* x_arg = (const float*)d_in[0];
    const float* x_ev  = (const float*)d_in[1];
    const float* Win   = (const float*)d_in[2];
    const float* b_in  = (const float*)d_in[3];
    const float* Wk    = (const float*)d_in[4];
    const float* bk    = (const float*)d_in[5];
    const float* Wq    = (const float*)d_in[6];
    const float* bq    = (const float*)d_in[7];
    const float* Wv    = (const float*)d_in[8];
    const float* bv    = (const float*)d_in[9];
    const float* Wa    = (const float*)d_in[10];
    const float* ba    = (const float*)d_in[11];
    const float* skip  = (const float*)d_in[12];
    const float* Watt  = (const float*)d_in[13];
    const float* Wmsg  = (const float*)d_in[14];
    const float* prel  = (const float*)d_in[15];
    const float* Wdeb  = (const float*)d_in[18];
    const float* bdeb  = (const float*)d_in[19];
    const float* Wvm   = (const float*)d_in[24];
    const float* bvm   = (const float*)d_in[25];
    const float* Wom   = (const float*)d_in[26];
    const float* bom   = (const float*)d_in[27];
    const float* Wc1   = (const float*)d_in[28];
    const float* bc1   = (const float*)d_in[29];
    const float* Wc2   = (const float*)d_in[30];
    const float* bc2   = (const float*)d_in[31];
    const int* e0s = (const int*)d_in[32];
    const int* e0d = (const int*)d_in[33];
    const int* e1s = (const int*)d_in[34];
    const int* e1d = (const int*)d_in[35];
    const int* e2s = (const int*)d_in[36];
    const int* e2d = (const int*)d_in[37];
    const int* batch = (const int*)d_in[38];
    float* outp = (float*)d_out;

    char* w = (char*)d_ws;
    size_t o = 0;
    auto alloc = [&](size_t bytes) -> char* {
        char* p = w + o;
        o = (o + bytes + 255) & ~(size_t)255;
        return p;
    };
    ushort* xs0  = (ushort*)alloc((size_t)N0 * 64 * 2);
    ushort* xs1  = (ushort*)alloc((size_t)N1 * 64 * 2);
    uchar* projAll = (uchar*)alloc((size_t)N0 * 384 + (size_t)N1 * 256);
    float* agg0  = (float*)alloc((size_t)N0 * 64 * 4);
    float* agg1  = (float*)alloc((size_t)N1 * 64 * 4);
    int* off0 = (int*)alloc((size_t)(N0 + 1) * 4);
    int* off1 = (int*)alloc((size_t)(N1 + 1) * 4);
    int* cnt0 = (int*)alloc((size_t)N0 * 4);
    int* cnt1 = (int*)alloc((size_t)N1 * 4);
    int* rec0 = (int*)alloc((size_t)(E0N + E1N) * 4);
    int* rec1 = (int*)alloc((size_t)E2N * 4);
    int* bsA  = (int*)alloc(256 * 4);
    int* bsB  = (int*)alloc(256 * 4);
    ushort* Wpack = (ushort*)alloc((size_t)16 * 4096 * 2);
    float* bpack = (float*)alloc((size_t)16 * 64 * 4);
    ushort* Wpin = (ushort*)alloc((size_t)2 * KSTEPS_IN * 2048 * 2);
    ushort* WaPack = (ushort*)alloc((size_t)4 * 4096 * 2);
    float* gsum = (float*)alloc((size_t)NG * 64 * 4);
    int* gcnt = (int*)alloc((size_t)NG * 4);
    if (o > ws_size) return;

    const int ZB = (N0 + N1 + NG * 64 + NG + 255) / 256;

    // 1. prep (fold + packs) + zero counters/pooling
    prep_zero_kernel<<<PREPB + ZB, 256, 0, stream>>>(
        Wq, bq, Wk, bk, Wv, bv, Watt, Wmsg, prel, Win, Wa,
        Wpack, bpack, Wpin, WaPack, cnt0, cnt1, (int*)gsum, gcnt);
    // 2. hist
    hist_all_kernel<<<1024, 256, 0, stream>>>(e0d, e1d, e2d, cnt0, cnt1);
    // 3-4. scans (scan2 folded into scan3)
    scan1_all_kernel<<<SB0 + SB1, 256, 0, stream>>>(cnt0, cnt1, off0, off1, bsA, bsB);
    scan3_all_kernel<<<SB0 + SB1, 256, 0, stream>>>(off0, off1, bsA, bsB);
    // 5. scatter
    scatter_all_kernel<<<1024, 256, 0, stream>>>(
        e0s, e0d, e1s, e1d, e2s, e2d, off0, off1, cnt0, cnt1, rec0, rec1);
    // 6. in_proj + proj l=0
    inproj_proj_kernel<<<GB0 + GB1, 256, 0, stream>>>(
        x_arg, x_ev, Wpin, b_in, xs0, xs1, Wpack, bpack, projAll);
    // 7. agg l=0
    agg_fused<<<AB0 + AB1, 256, 0, stream>>>(off0, rec0, off1, rec1, projAll, agg0, agg1);
    // 8. epi l=0 + proj l=1
    epi_kernel<1><<<GB0 + GB1, 256, 0, stream>>>(
        agg0, agg1, WaPack, ba, xs0, xs1, skip, 0, Wpack, bpack, projAll);
    // 9. agg l=1
    agg_fused<<<AB0 + AB1, 256, 0, stream>>>(off0, rec0, off1, rec1, projAll, agg0, agg1);
    // 10. epi l=1 (final)
    epi_kernel<0><<<GB0 + GB1, 256, 0, stream>>>(
        agg0, agg1, WaPack, ba, xs0, xs1, skip, 1, Wpack, bpack, projAll);
    // 11-12. pooling + head
    {
        int waves = (N0 + 255) / 256;
        segsum_kernel<<<(waves + 3) / 4, 256, 0, stream>>>(xs0, batch, N0, gsum, gcnt);
    }
    head_kernel<<<1, 256, 0, stream>>>(gsum, gcnt, Wdeb, bdeb, Wvm, bvm, Wom, bom,
                                       Wc1, bc1, Wc2, bc2, outp);
}